// Round 7
// baseline (110.069 us; speedup 1.0000x reference)
//
#include <hip/hip_runtime.h>
#include <hip/hip_bf16.h>
#include <hip/hip_fp16.h>

#define NB 4
#define NS 2048
#define NE 128
#define NH 16
#define ND 8

#define VT_BLK 144                 // shorts per 16-t block: 9 rows x 16 slots
#define VT_BH (128 * VT_BLK)       // shorts per (b,h): 128 blocks = 18432

typedef __attribute__((ext_vector_type(8))) _Float16 half8;
typedef __attribute__((ext_vector_type(4))) float f32x4;
typedef __attribute__((ext_vector_type(16))) float f32x16;

__device__ __forceinline__ unsigned int pkrtz(float a, float b) {
    typedef __fp16 fp16v2 __attribute__((ext_vector_type(2)));
    union { fp16v2 h; unsigned int u; } v;
    v.h = __builtin_amdgcn_cvt_pkrtz(a, b);
    return v.u;
}
__device__ __forceinline__ unsigned short f2h(float a) {
    return __half_as_ushort(__float2half(a));   // RNE
}
__device__ __forceinline__ half8 mk_half8(unsigned u0, unsigned u1,
                                          unsigned u2, unsigned u3) {
    union { half8 h; unsigned u[4]; } v;
    v.u[0] = u0; v.u[1] = u1; v.u[2] = u2; v.u[3] = u3;
    return v.h;
}

// cumprod-of-cos row: p[d] = prod_{i<=d} cos(x[i] + th[i])
__device__ __forceinline__ void qrow(const float* __restrict__ xp,
                                     const float* th, float* p) {
    float4 a = *(const float4*)xp, c = *(const float4*)(xp + 4);
    float t = 1.f;
    t *= cosf(a.x + th[0]); p[0] = t;
    t *= cosf(a.y + th[1]); p[1] = t;
    t *= cosf(a.z + th[2]); p[2] = t;
    t *= cosf(a.w + th[3]); p[3] = t;
    t *= cosf(c.x + th[4]); p[4] = t;
    t *= cosf(c.y + th[5]); p[5] = t;
    t *= cosf(c.z + th[6]); p[6] = t;
    t *= cosf(c.w + th[7]); p[7] = t;
}

// qgen: q once per (b,h,s). Outputs:
//   qg  [b][h][s][d] f16 pre-scaled by SC (A/B operand rows for attn)
//   vtg [b][h][blk=s/16][d=0..8][slot=0..15] f16: V^T in pi2-order per
//       16-t block (pi2(s) = (s&3)+8*((s>>2)&1)+4*(s>>3), an involution),
//       mask folded in; d=8 = mask/ones row -> softmax denominator.
// Block 0 also converts w -> wf16 once for the LDS-free proj.
__global__ __launch_bounds__(256) void qgen_kernel(
        const float* __restrict__ x,
        const float* __restrict__ theta,
        const int* __restrict__ mask,
        const float* __restrict__ w,
        unsigned short* __restrict__ qg,
        unsigned short* __restrict__ vtg,
        unsigned short* __restrict__ wf16) {
    const int gid = blockIdx.x * 256 + threadIdx.x;   // 0..65535
    const int bh = gid >> 10;           // (b,h), 0..63
    const int b = bh >> 4, h = bh & (NH - 1);
    const int j = gid & 1023;           // pair within (b,h)
    const int s0 = 2 * j;
    const float SC = 0.71421629f;       // sqrt(log2(e)/sqrt(8))

    if (blockIdx.x == 0) {              // one-time w -> f16 (row-major [n][k])
        for (int i = threadIdx.x; i < 2048; i += 256) {
            const float* wp = w + i * 8;
            float4 a = *(const float4*)wp, c = *(const float4*)(wp + 4);
            uint4 pk;
            pk.x = pkrtz(a.x, a.y); pk.y = pkrtz(a.z, a.w);
            pk.z = pkrtz(c.x, c.y); pk.w = pkrtz(c.z, c.w);
            *(uint4*)&wf16[i * 8] = pk;
        }
    }

    float th[ND];
#pragma unroll
    for (int d = 0; d < ND; d++) th[d] = theta[d];

    float p0[ND], p1[ND];
    qrow(x + ((size_t)(b * NS + s0) * NE + h * ND), th, p0);
    qrow(x + ((size_t)(b * NS + s0 + 1) * NE + h * ND), th, p1);
    const float mz0 = mask[b * NS + s0] ? 1.f : 0.f;
    const float mz1 = mask[b * NS + s0 + 1] ? 1.f : 0.f;

    uint4 qa, qb;
    qa.x = pkrtz(p0[0] * SC, p0[1] * SC);
    qa.y = pkrtz(p0[2] * SC, p0[3] * SC);
    qa.z = pkrtz(p0[4] * SC, p0[5] * SC);
    qa.w = pkrtz(p0[6] * SC, p0[7] * SC);
    qb.x = pkrtz(p1[0] * SC, p1[1] * SC);
    qb.y = pkrtz(p1[2] * SC, p1[3] * SC);
    qb.z = pkrtz(p1[4] * SC, p1[5] * SC);
    qb.w = pkrtz(p1[6] * SC, p1[7] * SC);
    *(uint4*)&qg[((size_t)bh * NS + s0) * ND] = qa;
    *(uint4*)&qg[((size_t)bh * NS + s0 + 1) * ND] = qb;

    // pi2 slot for s0 (even -> slot even; s0+1 lands in slot+1)
    const int blk = s0 >> 4, u = s0 & 15;
    const int k2 = (u & 3) | (((u >> 3) & 1) << 2) | (((u >> 2) & 1) << 3);
    unsigned short* vb = vtg + (size_t)bh * VT_BH + blk * VT_BLK + k2;
#pragma unroll
    for (int d = 0; d < ND; d++)
        *(unsigned int*)&vb[d * 16] = pkrtz(p0[d] * mz0, p1[d] * mz1);
    *(unsigned int*)&vb[8 * 16] = pkrtz(mz0, mz1);   // ones/mask row
}

// R14 attn: 32x32x16 MFMAs, ZERO LDS, ZERO barriers. Previous structure
// measured exactly the sum of its serial per-pipe costs (trans 14 + LDS 14 +
// VALU 8 + MFMA 3 ~= 40 us): pipes not overlapping; two occupancy fixes were
// neutral. This version deletes the LDS pipe and barriers entirely; operands
// come from L2-hot qg/vtg and the free-running stream lets the compiler
// software-pipeline loads across chunks.
//
// Wave owns 32 m-rows; 4 waves/block -> 128 m; grid 64bh x 16 = 1024.
// Scores: S^T tile = mfma_32x32x16(A = q_t rows, B = q_m cols, C = 0).
//   A: lane reads qg row tb+(l&31), 16B; lanes 32-63 broadcast-read the same
//      rows (their k=8..15 slots are garbage, killed by B's zeroed k8-15).
//   B: lane<32 = q_m[mb+l31][0..7] (k=d), lane>=32 = 0.
//   C-layout (verified, dtype-indep): col m = l&31, row t = (r&3)+8*(r>>2)+4*hi.
// PV: the C-layout IS the 32x32x16 A-layout under pi2: pA1 = pack(p[0..7])
//   covers t 0-15 (lane<32 supplies k0-7 = t {0-3,8-11}, lane>=32 k8-15 =
//   t {4-7,12-15}); pA2 = pack(p[8..15]) covers t 16-31. V^T staged pi2-
//   ordered -> B-frag is one contiguous 16B read per sub-block.
//   B cols 9..31 read the d=8 ones row (dup) -> unused O cols, finite.
// O col 8 = denominator (ones row). No running max needed (|s|<=4.08 log2).
__global__ __launch_bounds__(256) void attn_kernel(
        const unsigned short* __restrict__ qg,
        const unsigned short* __restrict__ vtg,
        unsigned short* __restrict__ mid) {            // f16 [B*S][NE]
    const int bid = blockIdx.x;
    const int bh = bid >> 4;
    const int b = bh >> 4, h = bh & (NH - 1);
    const int msix = bid & 15;
    const int tid = threadIdx.x;

    const int wave = tid >> 6, lane = tid & 63;
    const int l31 = lane & 31, hi = lane >> 5;
    const int mb = msix * 128 + wave * 32;

    // B operand (q_m): col = l31, k = hi*8+j; hi=0 real (k=d 0..7), hi=1 zero.
    half8 hz = {0, 0, 0, 0, 0, 0, 0, 0};
    half8 bm = hi ? hz : *(const half8*)&qg[((size_t)bh * NS + mb + l31) * ND];

    const unsigned short* qt = qg + (size_t)bh * NS * ND + (size_t)l31 * ND;
    const int dv = (l31 < 9) ? l31 : 8;
    const unsigned short* vb = vtg + (size_t)bh * VT_BH + dv * 16 + hi * 8;

    f32x16 O = {0.f};
    const f32x16 zc = {0.f};

    for (int ch = 0; ch < 64; ch++) {
        // A (q_t rows tb..tb+31; lanes 32-63 broadcast rows 0..31)
        half8 at = *(const half8*)&qt[(size_t)ch * 32 * ND];
        half8 vf1 = *(const half8*)&vb[ch * 2 * VT_BLK];
        half8 vf2 = *(const half8*)&vb[ch * 2 * VT_BLK + VT_BLK];

        f32x16 s = __builtin_amdgcn_mfma_f32_32x32x16_f16(at, bm, zc, 0, 0, 0);

        half8 pA1 = mk_half8(
            pkrtz(__builtin_amdgcn_exp2f(s[0]),  __builtin_amdgcn_exp2f(s[1])),
            pkrtz(__builtin_amdgcn_exp2f(s[2]),  __builtin_amdgcn_exp2f(s[3])),
            pkrtz(__builtin_amdgcn_exp2f(s[4]),  __builtin_amdgcn_exp2f(s[5])),
            pkrtz(__builtin_amdgcn_exp2f(s[6]),  __builtin_amdgcn_exp2f(s[7])));
        half8 pA2 = mk_half8(
            pkrtz(__builtin_amdgcn_exp2f(s[8]),  __builtin_amdgcn_exp2f(s[9])),
            pkrtz(__builtin_amdgcn_exp2f(s[10]), __builtin_amdgcn_exp2f(s[11])),
            pkrtz(__builtin_amdgcn_exp2f(s[12]), __builtin_amdgcn_exp2f(s[13])),
            pkrtz(__builtin_amdgcn_exp2f(s[14]), __builtin_amdgcn_exp2f(s[15])));

        O = __builtin_amdgcn_mfma_f32_32x32x16_f16(pA1, vf1, O, 0, 0, 0);
        O = __builtin_amdgcn_mfma_f32_32x32x16_f16(pA2, vf2, O, 0, 0, 0);
    }

    // ---- epilogue: denominator = O col 8 (lane 8/40 of this half) ----
#pragma unroll
    for (int r = 0; r < 16; r++) {
        float lsum = __shfl(O[r], (lane & 32) | 8, 64);
        float v = O[r] / lsum;
        if (l31 < ND) {
            int m = mb + (r & 3) + 8 * (r >> 2) + 4 * hi;
            mid[(size_t)(b * NS + m) * NE + h * ND + l31] = f2h(v);
        }
    }
}

// proj: LDS-free (R13). w pre-converted (wf16, 32 KB, L2-hot); each wave
// loads A (16 mid rows) + B (16 wf16 rows) straight from global, 4 MFMAs.
__global__ __launch_bounds__(512) void proj_kernel(
        const unsigned short* __restrict__ mid,
        const unsigned short* __restrict__ wf16,
        float* __restrict__ out) {
    const int rb = blockIdx.x * 16;
    const int tid = threadIdx.x;
    const int wavei = tid >> 6, lane = tid & 63;
    const int quad = lane >> 4, l15 = lane & 15;
    const int n0 = wavei * 16;

    f32x4 acc = {0.f, 0.f, 0.f, 0.f};
#pragma unroll
    for (int kt = 0; kt < 4; kt++) {
        half8 af = *(const half8*)&mid[(size_t)(rb + l15) * NE + kt * 32 + quad * 8];
        half8 bf = *(const half8*)&wf16[(n0 + l15) * NE + kt * 32 + quad * 8];
        acc = __builtin_amdgcn_mfma_f32_16x16x32_f16(af, bf, acc, 0, 0, 0);
    }
#pragma unroll
    for (int r = 0; r < 4; r++)
        out[(size_t)(rb + quad * 4 + r) * NE + n0 + l15] = acc[r];
}

extern "C" void kernel_launch(void* const* d_in, const int* in_sizes, int n_in,
                              void* d_out, int out_size, void* d_ws, size_t ws_size,
                              hipStream_t stream) {
    const float* x     = (const float*)d_in[0];
    const float* theta = (const float*)d_in[1];
    const float* w_out = (const float*)d_in[2];
    const int*   mask  = (const int*)d_in[3];
    float* out = (float*)d_out;

    // workspace: mid (2 MB) | qg (2 MB) | vtg (2.36 MB) | wf16 (32 KB)
    unsigned short* mid16 = (unsigned short*)d_ws;
    unsigned short* qg   = mid16 + (size_t)NB * NS * NE;           // 1,048,576 shorts
    unsigned short* vtg  = qg + (size_t)NB * NH * NS * ND;         // 1,048,576 shorts
    unsigned short* wf16 = vtg + (size_t)NB * NH * VT_BH;          // 1,179,648 shorts

    qgen_kernel<<<NB * NH * NS / 2 / 256, 256, 0, stream>>>(x, theta, mask, w_out,
                                                            qg, vtg, wf16);
    attn_kernel<<<NB * NH * 16, 256, 0, stream>>>(qg, vtg, mid16);
    proj_kernel<<<NB * NS / 16, 512, 0, stream>>>(mid16, wf16, out);
}